// Round 11
// baseline (855.363 us; speedup 1.0000x reference)
//
#include <hip/hip_runtime.h>

typedef __attribute__((ext_vector_type(8))) short short8;
typedef __attribute__((ext_vector_type(4))) float f32x4;
typedef __attribute__((ext_vector_type(4))) unsigned int u32x4;

#define MFMA16(a, b, c) __builtin_amdgcn_mfma_f32_16x16x32_bf16((a), (b), (c), 0, 0, 0)

// acc1 lives in AGPRs: inline-asm MFMA with "a"-class accumulator. The 512-thr
// arch-VGPR cap is 128 (measured R6/R9/R10: launch_bounds arg2, block size,
// amdgpu_waves_per_eu all refused to lift it); AGPRs are a separate budget.
__device__ __forceinline__ void mfma_a(f32x4& acc, short8 a, short8 b) {
  asm volatile("v_mfma_f32_16x16x32_bf16 %0, %1, %2, %0"
               : "+a"(acc) : "v"(a), "v"(b));
}
// AGPR scalar home for cold per-thread state (c-states): frees 32 arch VGPRs.
__device__ __forceinline__ float a_rd(const float& a) {
  float v; asm volatile("v_accvgpr_read_b32 %0, %1" : "=v"(v) : "a"(a)); return v;
}
__device__ __forceinline__ void a_wr(float& a, float v) {
  asm volatile("v_accvgpr_write_b32 %0, %1" : "=a"(a) : "v"(v));
}

// LDS-only barrier (R8, proven): drain lgkmcnt, fence scheduler, s_barrier.
#define BAR_LDS()                                                  \
  do {                                                             \
    asm volatile("s_waitcnt lgkmcnt(0)" ::: "memory");             \
    __builtin_amdgcn_sched_barrier(0);                             \
    __builtin_amdgcn_s_barrier();                                  \
    __builtin_amdgcn_sched_barrier(0);                             \
  } while (0)

__device__ __forceinline__ unsigned short f2bf(float f) {
  unsigned int u = __builtin_bit_cast(unsigned int, f);
  u += 0x7fffu + ((u >> 16) & 1u);   // RNE
  return (unsigned short)(u >> 16);
}
__device__ __forceinline__ float bf2f(unsigned short s) {
  unsigned int u = ((unsigned int)s) << 16;
  return __builtin_bit_cast(float, u);
}
__device__ __forceinline__ unsigned cvtpk(float lo, float hi) {
  unsigned r;
  asm("v_cvt_pk_bf16_f32 %0, %1, %2" : "=v"(r) : "v"(lo), "v"(hi));
  return r;
}

// Fused LSTM element update, bias folded into the exp2 fmas.
__device__ __forceinline__ void lstm_elem(float gi, float gf, float gg, float go,
                                          float nbi, float nbf, float pbg, float nbo,
                                          float& c, float& h) {
  const float L1 = 1.44269504f, L2 = 2.88539008f;
  float A = __builtin_amdgcn_exp2f(__builtin_fmaf(-L1, gi, nbi));
  float B = __builtin_amdgcn_exp2f(__builtin_fmaf(L2, gg, pbg));
  float t1 = 1.0f + B;
  float den = __builtin_amdgcn_rcpf(__builtin_fmaf(A, t1, t1));
  float it = (B - 1.0f) * den;                       // sig(i)*tanh(g)
  float F = __builtin_amdgcn_rcpf(1.0f + __builtin_amdgcn_exp2f(__builtin_fmaf(-L1, gf, nbf)));
  c = __builtin_fmaf(F, c, it);
  float C = __builtin_amdgcn_exp2f(L2 * c);
  float O = __builtin_amdgcn_exp2f(__builtin_fmaf(-L1, go, nbo));
  float t2 = 1.0f + C;
  float den2 = __builtin_amdgcn_rcpf(__builtin_fmaf(O, t2, t2));
  h = (C - 1.0f) * den2;                             // sig(o)*tanh(c)
}

// ---------------------------------------------------------------------------
// Prep: swizzle weights into MFMA B-fragment-linear bf16 layout.
// ---------------------------------------------------------------------------
__global__ void prep_weights(const float* __restrict__ w_ih_l0, const float* __restrict__ w_hh_l0,
                             const float* __restrict__ w_ih_l1, const float* __restrict__ w_hh_l1,
                             unsigned short* __restrict__ W0f, unsigned short* __restrict__ W1f) {
  int tid = blockIdx.x * blockDim.x + threadIdx.x;
  if (tid < 32 * 5 * 64) {
    int nt = tid / 320, rem = tid % 320;
    int kc = rem / 64, lane = rem % 64;
    int g = nt * 16 + (lane & 15);
    int k0 = kc * 32 + (lane >> 4) * 8;
    short8 s;
#pragma unroll
    for (int j = 0; j < 8; ++j) {
      int k = k0 + j;
      float val;
      if (k < 28) val = w_ih_l0[g * 28 + k];
      else if (k < 32) val = 0.0f;
      else val = w_hh_l0[g * 128 + (k - 32)];
      s[j] = (short)f2bf(val);
    }
    *(short8*)(W0f + (size_t)tid * 8) = s;
  } else if (tid < 32 * 5 * 64 + 32 * 8 * 64) {
    int id = tid - 32 * 5 * 64;
    int nt = id / 512, rem = id % 512;
    int kc = rem / 64, lane = rem % 64;
    int g = nt * 16 + (lane & 15);
    int k0 = kc * 32 + (lane >> 4) * 8;
    short8 s;
#pragma unroll
    for (int j = 0; j < 8; ++j) {
      int k = k0 + j;
      float val = (k < 128) ? w_ih_l1[g * 128 + k] : w_hh_l1[g * 128 + (k - 128)];
      s[j] = (short)f2bf(val);
    }
    *(short8*)(W1f + (size_t)id * 8) = s;
  }
}

// ---------------------------------------------------------------------------
// Fused 2-layer LSTM. 256 blocks x 512 threads (8 waves) = 1 block/CU.
// Block owns 64 batch rows; wave wv = n-slice (16 h-cols x 4 gates), 4 m-tiles.
//
// PHASE ROTATION (R7 schedule, HW-correct 3x) with the register split that
// finally fits: acc0 in VGPRs (builtin MFMA), acc1 + c-states in AGPRs
// (inline-asm MFMA "+a", accvgpr_read/write). Arch-VGPR peak ~124 < 128 cap.
//   phase1: E0(t)->seg0[p]  || A1b: acc1  = h1(t-1)[seg1[q]] @ W1hh(kc4-7)
//   bar1
//   phase2:                    A1a: acc1 += h0(t)[seg0[p]]   @ W1ih(kc0-3)
//   phase3: E1(t)->seg1[p]  || A0(t+1): x(t+1)@W0kc0 + h0(t)@W0hh(kc1-4)
//   bar2
// s_nop pair before E1's first VALU read of acc1 (asm MFMA latency is opaque
// to the scheduler). acc1 zero-init sits before phase1's load cluster.
// LDS 64 KiB: seg(layer,p) = (layer*2+p)*16384; element (row,col) at
// byte row*256 + (((col>>3)^(row&15))<<4) + (col&7)*2
// ---------------------------------------------------------------------------
__global__ __launch_bounds__(512) void lstm_fused(
    const float* __restrict__ x,
    const float* __restrict__ b_ih_l0, const float* __restrict__ b_hh_l0,
    const float* __restrict__ b_ih_l1, const float* __restrict__ b_hh_l1,
    const float* __restrict__ fc_w, const float* __restrict__ fc_b,
    const unsigned short* __restrict__ W0f, const unsigned short* __restrict__ W1f,
    float* __restrict__ out) {
  __shared__ __align__(16) char hls[4 * 16384];

  const int tid = (int)threadIdx.x;
  const int wv = tid >> 6;          // wave 0..7 = n-slice
  const int lane = tid & 63;
  const int lr = lane & 15;         // A: m-row / B: n-col / D: col
  const int lq = lane >> 4;         // k-quad / D row group
  const int b0 = (int)blockIdx.x * 64;

  for (int i = tid; i < 16384; i += 512) ((unsigned*)hls)[i] = 0u;

  // Premultiplied bias scalars: q0/q1/q3 -> -L1*b, q2 -> +L2*b.
  const float L1 = 1.44269504f, L2 = 2.88539008f;
  float nb0[4], nb1[4];
#pragma unroll
  for (int q = 0; q < 4; ++q) {
    int g = q * 128 + wv * 16 + lr;
    float s0 = b_ih_l0[g] + b_hh_l0[g];
    float s1 = b_ih_l1[g] + b_hh_l1[g];
    float sc = (q == 2) ? L2 : -L1;
    nb0[q] = sc * s0;
    nb1[q] = sc * s1;
  }
  const f32x4 zero4 = {0.0f, 0.0f, 0.0f, 0.0f};

  // Read base (A-frag, row m*16+lr, k-chunk kc): addr = (rbB+seg) ^ (kc<<6) + m*4096
  const unsigned rbB = (unsigned)(lr * 256 + ((lq ^ lr) << 4));
  // Write base (D elem row m*16+lq*4+r): addr = (wbB+seg) ^ (r<<4) + m*4096 + r*256
  const unsigned cwl = (unsigned)((wv * 2 + (lr >> 3)) ^ (lq << 2));
  const unsigned wbB = (unsigned)(lq * 1024 + (cwl << 4) + (lr & 7) * 2);
  // Weight byte-offset bases (32-bit; q/kc strides are compile-time).
  const unsigned wB0 = (unsigned)((wv * 320 + lane) * 16);
  const unsigned wB1 = (unsigned)((wv * 512 + lane) * 16);
  const unsigned xo0 = (unsigned)(((b0 + lr) * 784 + lq * 8) * 4);

  // c-states in AGPRs (accessed only via a_rd/a_wr with static indices).
  float c0a[4][4], c1a[4][4];
#pragma unroll
  for (int m = 0; m < 4; ++m)
#pragma unroll
    for (int r = 0; r < 4; ++r) { a_wr(c0a[m][r], 0.0f); a_wr(c1a[m][r], 0.0f); }

  f32x4 acc0[4][4];   // VGPR accumulator (builtin MFMA)
  f32x4 acc1[4][4];   // AGPR accumulator (asm MFMA "+a")

  __syncthreads();

  // ---- Prologue: A0(0). h0(-1)=0 -> only the x/kc0 term. -------------------
  {
    short8 ax[4];
#pragma unroll
    for (int m = 0; m < 4; ++m) {
      const unsigned xo = xo0 + (unsigned)(m * 50176);
      f32x4 u0 = *(const f32x4*)((const char*)x + xo);
      f32x4 u1 = {0.0f, 0.0f, 0.0f, 0.0f};
      if (lq < 3) u1 = *(const f32x4*)((const char*)x + xo + 16);
      u32x4 up;
      up[0] = cvtpk(u0[0], u0[1]);
      up[1] = cvtpk(u0[2], u0[3]);
      up[2] = cvtpk(u1[0], u1[1]);
      up[3] = cvtpk(u1[2], u1[3]);
      ax[m] = __builtin_bit_cast(short8, up);
    }
    short8 bq[4];
#pragma unroll
    for (int q = 0; q < 4; ++q)
      bq[q] = *(const short8*)((const char*)W0f + (wB0 + (unsigned)(q * 40960)));
#pragma unroll
    for (int m = 0; m < 4; ++m)
#pragma unroll
      for (int q = 0; q < 4; ++q) acc0[m][q] = MFMA16(ax[m], bq[q], zero4);
  }

  for (int t = 0; t < 28; ++t) {
    const unsigned sp = (unsigned)(t & 1) << 14;   // seg offset, parity p
    const unsigned sq = sp ^ 16384u;               // parity 1-p

    // ======== phase 1: E0(t) -> seg0[p]  ||  A1b: acc1 = h1(t-1)@W1hh ======
    {
      // zero-init acc1 (accvgpr_write) early: loads below give hazard spacing
      // before the first asm MFMA reads it as srcC.
#pragma unroll
      for (int m = 0; m < 4; ++m)
#pragma unroll
        for (int q = 0; q < 4; ++q) acc1[m][q] = zero4;

      const unsigned rh1 = rbB + 32768u + sq;
      const unsigned wa = wbB + sp;
#pragma unroll
      for (int j = 0; j < 4; ++j) {
        // A1b chunk kc=4+j -> acc1 (AGPR)
        short8 bq[4];
#pragma unroll
        for (int q = 0; q < 4; ++q)
          bq[q] = *(const short8*)((const char*)W1f + (wB1 + (unsigned)(q * 65536 + (4 + j) * 1024)));
        short8 am[4];
#pragma unroll
        for (int m = 0; m < 4; ++m)
          am[m] = *(const short8*)(hls + ((rh1 ^ (unsigned)(j * 64)) + m * 4096));
#pragma unroll
        for (int m = 0; m < 4; ++m)
#pragma unroll
          for (int q = 0; q < 4; ++q) mfma_a(acc1[m][q], am[m], bq[q]);
        // E0 m-tile j (independent; scheduler meshes trans with MFMA)
        float hv[4];
#pragma unroll
        for (int r = 0; r < 4; ++r) {
          float c = a_rd(c0a[j][r]), h;
          lstm_elem(acc0[j][0][r], acc0[j][1][r], acc0[j][2][r], acc0[j][3][r],
                    nb0[0], nb0[1], nb0[2], nb0[3], c, h);
          a_wr(c0a[j][r], c); hv[r] = h;
        }
        unsigned u01 = cvtpk(hv[0], hv[1]);
        unsigned u23 = cvtpk(hv[2], hv[3]);
        *(unsigned short*)(hls + ((wa ^ 0u)  + j * 4096 + 0))   = (unsigned short)u01;
        *(unsigned short*)(hls + ((wa ^ 16u) + j * 4096 + 256)) = (unsigned short)(u01 >> 16);
        *(unsigned short*)(hls + ((wa ^ 32u) + j * 4096 + 512)) = (unsigned short)u23;
        *(unsigned short*)(hls + ((wa ^ 48u) + j * 4096 + 768)) = (unsigned short)(u23 >> 16);
      }
    }

    BAR_LDS();   // bar1: h0(t) visible (also separates seg WAR pairs)

    // ======== phase 2: A1a: acc1 += h0(t)[seg0[p]] @ W1ih(kc0-3) ===========
    {
      const unsigned rh0 = rbB + sp;
#pragma unroll 2
      for (int kc = 0; kc < 4; ++kc) {
        short8 bq[4];
#pragma unroll
        for (int q = 0; q < 4; ++q)
          bq[q] = *(const short8*)((const char*)W1f + (wB1 + (unsigned)(q * 65536 + kc * 1024)));
        short8 am[4];
#pragma unroll
        for (int m = 0; m < 4; ++m)
          am[m] = *(const short8*)(hls + ((rh0 ^ (unsigned)(kc * 64)) + m * 4096));
#pragma unroll
        for (int m = 0; m < 4; ++m)
#pragma unroll
          for (int q = 0; q < 4; ++q) mfma_a(acc1[m][q], am[m], bq[q]);
      }
    }

    // Hazard spacing: asm MFMA latency is invisible to the scheduler; E1's
    // VALU reads of acc1 follow closely.
    asm volatile("s_nop 7\n\ts_nop 7");

    // ======== phase 3: E1(t) -> seg1[p]  ||  A0(t+1) from h0(t)+x(t+1) ====
    {
      const unsigned wa = wbB + 32768u + sp;
      if (t < 27) {
        // A0 kc0: x(t+1) fragment (global loads issue at block top)
        const char* xb = (const char*)x + (unsigned)((t + 1) * 112);
        short8 ax[4];
#pragma unroll
        for (int m = 0; m < 4; ++m) {
          const unsigned xo = xo0 + (unsigned)(m * 50176);
          f32x4 u0 = *(const f32x4*)(xb + xo);
          f32x4 u1 = {0.0f, 0.0f, 0.0f, 0.0f};
          if (lq < 3) u1 = *(const f32x4*)(xb + xo + 16);
          u32x4 up;
          up[0] = cvtpk(u0[0], u0[1]);
          up[1] = cvtpk(u0[2], u0[3]);
          up[2] = cvtpk(u1[0], u1[1]);
          up[3] = cvtpk(u1[2], u1[3]);
          ax[m] = __builtin_bit_cast(short8, up);
        }
        short8 bq0[4];
#pragma unroll
        for (int q = 0; q < 4; ++q)
          bq0[q] = *(const short8*)((const char*)W0f + (wB0 + (unsigned)(q * 40960)));
#pragma unroll
        for (int m = 0; m < 4; ++m)
#pragma unroll
          for (int q = 0; q < 4; ++q) acc0[m][q] = MFMA16(ax[m], bq0[q], zero4);

        const unsigned r0 = rbB + sp;   // h0(t) in seg0[p]
#pragma unroll
        for (int j = 0; j < 4; ++j) {
          // A0 chunk kc=1+j -> acc0 (VGPR, builtin)
          short8 bq[4];
#pragma unroll
          for (int q = 0; q < 4; ++q)
            bq[q] = *(const short8*)((const char*)W0f + (wB0 + (unsigned)(q * 40960 + (1 + j) * 1024)));
          short8 am[4];
#pragma unroll
          for (int m = 0; m < 4; ++m)
            am[m] = *(const short8*)(hls + ((r0 ^ (unsigned)(j * 64)) + m * 4096));
#pragma unroll
          for (int m = 0; m < 4; ++m)
#pragma unroll
            for (int q = 0; q < 4; ++q) acc0[m][q] = MFMA16(am[m], bq[q], acc0[m][q]);
          // E1 m-tile j (reads acc1 from AGPRs)
          float hv[4];
#pragma unroll
          for (int r = 0; r < 4; ++r) {
            float c = a_rd(c1a[j][r]), h;
            lstm_elem(acc1[j][0][r], acc1[j][1][r], acc1[j][2][r], acc1[j][3][r],
                      nb1[0], nb1[1], nb1[2], nb1[3], c, h);
            a_wr(c1a[j][r], c); hv[r] = h;
          }
          unsigned u01 = cvtpk(hv[0], hv[1]);
          unsigned u23 = cvtpk(hv[2], hv[3]);
          *(unsigned short*)(hls + ((wa ^ 0u)  + j * 4096 + 0))   = (unsigned short)u01;
          *(unsigned short*)(hls + ((wa ^ 16u) + j * 4096 + 256)) = (unsigned short)(u01 >> 16);
          *(unsigned short*)(hls + ((wa ^ 32u) + j * 4096 + 512)) = (unsigned short)u23;
          *(unsigned short*)(hls + ((wa ^ 48u) + j * 4096 + 768)) = (unsigned short)(u23 >> 16);
        }
      } else {
        // t == 27: E1 only
#pragma unroll
        for (int j = 0; j < 4; ++j) {
          float hv[4];
#pragma unroll
          for (int r = 0; r < 4; ++r) {
            float c = a_rd(c1a[j][r]), h;
            lstm_elem(acc1[j][0][r], acc1[j][1][r], acc1[j][2][r], acc1[j][3][r],
                      nb1[0], nb1[1], nb1[2], nb1[3], c, h);
            a_wr(c1a[j][r], c); hv[r] = h;
          }
          unsigned u01 = cvtpk(hv[0], hv[1]);
          unsigned u23 = cvtpk(hv[2], hv[3]);
          *(unsigned short*)(hls + ((wa ^ 0u)  + j * 4096 + 0))   = (unsigned short)u01;
          *(unsigned short*)(hls + ((wa ^ 16u) + j * 4096 + 256)) = (unsigned short)(u01 >> 16);
          *(unsigned short*)(hls + ((wa ^ 32u) + j * 4096 + 512)) = (unsigned short)u23;
          *(unsigned short*)(hls + ((wa ^ 48u) + j * 4096 + 768)) = (unsigned short)(u23 >> 16);
        }
      }
    }

    BAR_LDS();   // bar2: h1(t) visible
  }

  // ---------------- final h_n / c_n stores --------------------------------
  // t=27 parity p=1: h0(27) in seg0[1] = +16384, h1(27) in seg1[1] = +49152.
  {
    const unsigned wa0 = wbB + 16384u;
    const unsigned wa1 = wbB + 49152u;
#pragma unroll
    for (int m = 0; m < 4; ++m)
#pragma unroll
      for (int r = 0; r < 4; ++r) {
        int row = m * 16 + lq * 4 + r, col = wv * 16 + lr;
        size_t o = (size_t)(b0 + row) * 128 + col;
        unsigned roff = (unsigned)(r << 4);
        float h0 = bf2f(*(const unsigned short*)(hls + ((wa0 ^ roff) + m * 4096 + r * 256)));
        float h1 = bf2f(*(const unsigned short*)(hls + ((wa1 ^ roff) + m * 4096 + r * 256)));
        out[163840 + o] = h0;                 // h_n layer 0
        out[4358144 + o] = a_rd(c0a[m][r]);   // c_n layer 0
        out[2260992 + o] = h1;                // h_n layer 1
        out[6455296 + o] = a_rd(c1a[m][r]);   // c_n layer 1
      }
  }

  // ---------------- logits = h1(27) @ fc_w^T + fc_b ------------------------
  // Final BAR_LDS (bar2 at t=27) already made seg1[1] visible to all threads.
  for (int it = tid; it < 640; it += 512) {
    const unsigned short* h1f = (const unsigned short*)(hls + 49152);
    int bl = it / 10, o = it % 10;
    float s = fc_b[o];
#pragma unroll
    for (int kc8 = 0; kc8 < 16; ++kc8) {
      short8 hv = *(const short8*)(h1f + bl * 128 + ((kc8 ^ (bl & 15)) << 3));
      const float* wp = fc_w + o * 128 + kc8 * 8;
#pragma unroll
      for (int j = 0; j < 8; ++j) s += bf2f((unsigned short)hv[j]) * wp[j];
    }
    out[(size_t)(b0 + bl) * 10 + o] = s;
  }
}

extern "C" void kernel_launch(void* const* d_in, const int* in_sizes, int n_in,
                              void* d_out, int out_size, void* d_ws, size_t ws_size,
                              hipStream_t stream) {
  const float* x       = (const float*)d_in[0];
  const float* w_ih_l0 = (const float*)d_in[1];
  const float* w_hh_l0 = (const float*)d_in[2];
  const float* b_ih_l0 = (const float*)d_in[3];
  const float* b_hh_l0 = (const float*)d_in[4];
  const float* w_ih_l1 = (const float*)d_in[5];
  const float* w_hh_l1 = (const float*)d_in[6];
  const float* b_ih_l1 = (const float*)d_in[7];
  const float* b_hh_l1 = (const float*)d_in[8];
  const float* fc_w    = (const float*)d_in[9];
  const float* fc_b    = (const float*)d_in[10];

  unsigned short* W0f = (unsigned short*)d_ws;            // 32*5*64*8 = 81920 ush
  unsigned short* W1f = W0f + 32 * 5 * 64 * 8;            // 32*8*64*8 = 131072 ush
  float* out = (float*)d_out;

  hipLaunchKernelGGL(prep_weights, dim3(104), dim3(256), 0, stream,
                     w_ih_l0, w_hh_l0, w_ih_l1, w_hh_l1, W0f, W1f);
  hipLaunchKernelGGL(lstm_fused, dim3(256), dim3(512), 0, stream,
                     x, b_ih_l0, b_hh_l0, b_ih_l1, b_hh_l1, fc_w, fc_b, W0f, W1f, out);
}

// Round 12
// 446.107 us; speedup vs baseline: 1.9174x; 1.9174x over previous
//
#include <hip/hip_runtime.h>

typedef __attribute__((ext_vector_type(8))) short short8;
typedef __attribute__((ext_vector_type(4))) float f32x4;
typedef __attribute__((ext_vector_type(4))) unsigned int u32x4;

#define MFMA16(a, b, c) __builtin_amdgcn_mfma_f32_16x16x32_bf16((a), (b), (c), 0, 0, 0)

// LDS-only barrier (R8, proven): drain lgkmcnt, fence scheduler, s_barrier.
#define BAR_LDS()                                                  \
  do {                                                             \
    asm volatile("s_waitcnt lgkmcnt(0)" ::: "memory");             \
    __builtin_amdgcn_sched_barrier(0);                             \
    __builtin_amdgcn_s_barrier();                                  \
    __builtin_amdgcn_sched_barrier(0);                             \
  } while (0)

__device__ __forceinline__ unsigned short f2bf(float f) {
  unsigned int u = __builtin_bit_cast(unsigned int, f);
  u += 0x7fffu + ((u >> 16) & 1u);   // RNE
  return (unsigned short)(u >> 16);
}
__device__ __forceinline__ float bf2f(unsigned short s) {
  unsigned int u = ((unsigned int)s) << 16;
  return __builtin_bit_cast(float, u);
}
__device__ __forceinline__ unsigned cvtpk(float lo, float hi) {
  unsigned r;
  asm("v_cvt_pk_bf16_f32 %0, %1, %2" : "=v"(r) : "v"(lo), "v"(hi));
  return r;
}

// Fused LSTM element update, bias folded into the exp2 fmas.
__device__ __forceinline__ void lstm_elem(float gi, float gf, float gg, float go,
                                          float nbi, float nbf, float pbg, float nbo,
                                          float& c, float& h) {
  const float L1 = 1.44269504f, L2 = 2.88539008f;
  float A = __builtin_amdgcn_exp2f(__builtin_fmaf(-L1, gi, nbi));
  float B = __builtin_amdgcn_exp2f(__builtin_fmaf(L2, gg, pbg));
  float t1 = 1.0f + B;
  float den = __builtin_amdgcn_rcpf(__builtin_fmaf(A, t1, t1));
  float it = (B - 1.0f) * den;                       // sig(i)*tanh(g)
  float F = __builtin_amdgcn_rcpf(1.0f + __builtin_amdgcn_exp2f(__builtin_fmaf(-L1, gf, nbf)));
  c = __builtin_fmaf(F, c, it);
  float C = __builtin_amdgcn_exp2f(L2 * c);
  float O = __builtin_amdgcn_exp2f(__builtin_fmaf(-L1, go, nbo));
  float t2 = 1.0f + C;
  float den2 = __builtin_amdgcn_rcpf(__builtin_fmaf(O, t2, t2));
  h = (C - 1.0f) * den2;                             // sig(o)*tanh(c)
}

// ---------------------------------------------------------------------------
// Prep: swizzle weights into MFMA B-fragment-linear bf16 layout.
// ---------------------------------------------------------------------------
__global__ void prep_weights(const float* __restrict__ w_ih_l0, const float* __restrict__ w_hh_l0,
                             const float* __restrict__ w_ih_l1, const float* __restrict__ w_hh_l1,
                             unsigned short* __restrict__ W0f, unsigned short* __restrict__ W1f) {
  int tid = blockIdx.x * blockDim.x + threadIdx.x;
  if (tid < 32 * 5 * 64) {
    int nt = tid / 320, rem = tid % 320;
    int kc = rem / 64, lane = rem % 64;
    int g = nt * 16 + (lane & 15);
    int k0 = kc * 32 + (lane >> 4) * 8;
    short8 s;
#pragma unroll
    for (int j = 0; j < 8; ++j) {
      int k = k0 + j;
      float val;
      if (k < 28) val = w_ih_l0[g * 28 + k];
      else if (k < 32) val = 0.0f;
      else val = w_hh_l0[g * 128 + (k - 32)];
      s[j] = (short)f2bf(val);
    }
    *(short8*)(W0f + (size_t)tid * 8) = s;
  } else if (tid < 32 * 5 * 64 + 32 * 8 * 64) {
    int id = tid - 32 * 5 * 64;
    int nt = id / 512, rem = id % 512;
    int kc = rem / 64, lane = rem % 64;
    int g = nt * 16 + (lane & 15);
    int k0 = kc * 32 + (lane >> 4) * 8;
    short8 s;
#pragma unroll
    for (int j = 0; j < 8; ++j) {
      int k = k0 + j;
      float val = (k < 128) ? w_ih_l1[g * 128 + k] : w_hh_l1[g * 128 + (k - 128)];
      s[j] = (short)f2bf(val);
    }
    *(short8*)(W1f + (size_t)id * 8) = s;
  }
}

// ---------------------------------------------------------------------------
// Fused 2-layer LSTM — STAGGERED WAVE GROUPS. 256 blocks x 512 threads.
// Group A = waves 0-3 (rows 0-31), group B = waves 4-7 (rows 32-63); each
// group covers all 128 h-cols (32 cols/wave -> acc[2 m][8 qc], 64 VGPRs).
// Groups share NO LDS rows -> no cross-group hazards. B runs one half-step
// behind A, so at every barrier interval each SIMD has one wave in an MFMA
// phase and one in a trans-heavy epilogue phase (m114 cross-wave MFMA||VALU
// overlap). No accumulator crosses a barrier -> no 2-acc register wall
// (rotation retired: R7/R9/R10/R11 all spilled; gfx950 VGPR/AGPR unified).
//   even step: A L0half(t)  || B L1half(t-1);  BAR
//   odd  step: A L1half(t)  || B L0half(t);    BAR
// Per-wave weight loads double (8 frags/kc) -> ~6 GB L2 stream, < ceiling.
// #pragma unroll 1 on kc loops: latency hidden by the other group, not ILP.
// LDS 64 KiB: seg(layer,p) = (layer*2+p)*16384; element (row,col) at
// byte row*256 + (((col>>3)^(row&15))<<4) + (col&7)*2
// ---------------------------------------------------------------------------
__global__ __launch_bounds__(512) void lstm_fused(
    const float* __restrict__ x,
    const float* __restrict__ b_ih_l0, const float* __restrict__ b_hh_l0,
    const float* __restrict__ b_ih_l1, const float* __restrict__ b_hh_l1,
    const float* __restrict__ fc_w, const float* __restrict__ fc_b,
    const unsigned short* __restrict__ W0f, const unsigned short* __restrict__ W1f,
    float* __restrict__ out) {
  __shared__ __align__(16) char hls[4 * 16384];

  const int tid = (int)threadIdx.x;
  const int wv = tid >> 6;
  const int g = wv >> 2;            // 0: rows 0-31 (group A), 1: rows 32-63 (B)
  const int gw = wv & 3;            // n-quarter: h-cols [32gw, 32gw+32)
  const int lane = tid & 63;
  const int lr = lane & 15;
  const int lq = lane >> 4;
  const int b0 = (int)blockIdx.x * 64;

  for (int i = tid; i < 16384; i += 512) ((unsigned*)hls)[i] = 0u;

  // Premultiplied bias: nb[q][cc]; q0/q1/q3 -> -L1*b, q2 -> +L2*b.
  const float L1 = 1.44269504f, L2 = 2.88539008f;
  float nb0[4][2], nb1[4][2];
#pragma unroll
  for (int q = 0; q < 4; ++q)
#pragma unroll
    for (int cc = 0; cc < 2; ++cc) {
      int gi = q * 128 + gw * 32 + cc * 16 + lr;
      float s0 = b_ih_l0[gi] + b_hh_l0[gi];
      float s1 = b_ih_l1[gi] + b_hh_l1[gi];
      float sc = (q == 2) ? L2 : -L1;
      nb0[q][cc] = sc * s0;
      nb1[q][cc] = sc * s1;
    }
  const f32x4 zero4 = {0.0f, 0.0f, 0.0f, 0.0f};

  // A-frag read base (row g*32+m*16+lr, h-chunk j): ((rbB+seg) ^ (j<<6)) + m*4096
  const unsigned rbB = (unsigned)(g * 8192 + lr * 256 + ((lq ^ lr) << 4));
  // D write bases per cc: ((wbBc+seg) ^ (r<<4)) + m*4096 + r*256
  unsigned wbBc[2];
#pragma unroll
  for (int cc = 0; cc < 2; ++cc) {
    unsigned swz = (unsigned)((gw * 4 + cc * 2 + (lr >> 3)) ^ (lq << 2));
    wbBc[cc] = (unsigned)(g * 8192 + lq * 1024 + (swz << 4) + (lr & 7) * 2);
  }
  // Weight bases: frag(q, nt2=gw*2+cc, kc) at wb + cc*ntS + q*qS + kc*1024
  const unsigned wb0 = (unsigned)(gw * 2 * 5120 + lane * 16);   // W0f: ntS=5120, qS=40960
  const unsigned wb1 = (unsigned)(gw * 2 * 8192 + lane * 16);   // W1f: ntS=8192, qS=65536
  const unsigned xoB = (unsigned)(((b0 + g * 32 + lr) * 784 + lq * 8) * 4);

  float c0s[2][2][4], c1s[2][2][4];   // [m][cc][r]
#pragma unroll
  for (int m = 0; m < 2; ++m)
#pragma unroll
    for (int cc = 0; cc < 2; ++cc)
#pragma unroll
      for (int r = 0; r < 4; ++r) { c0s[m][cc][r] = 0.0f; c1s[m][cc][r] = 0.0f; }

  __syncthreads();

  // ---- half-step bodies (complete layer: mfma + epilogue, 1 barrier after) --
  auto L0half = [&](int t) {
    const unsigned sp = (unsigned)(t & 1) << 14;
    const unsigned sq = sp ^ 16384u;
    f32x4 acc[2][8];   // [m][q*2+cc]
    // kc0: x(t)
    {
      const char* xb = (const char*)x + (unsigned)(t * 112);
      short8 ax[2];
#pragma unroll
      for (int m = 0; m < 2; ++m) {
        const unsigned xo = xoB + (unsigned)(m * 50176);
        f32x4 u0 = *(const f32x4*)(xb + xo);
        f32x4 u1 = {0.0f, 0.0f, 0.0f, 0.0f};
        if (lq < 3) u1 = *(const f32x4*)(xb + xo + 16);
        u32x4 up;
        up[0] = cvtpk(u0[0], u0[1]);
        up[1] = cvtpk(u0[2], u0[3]);
        up[2] = cvtpk(u1[0], u1[1]);
        up[3] = cvtpk(u1[2], u1[3]);
        ax[m] = __builtin_bit_cast(short8, up);
      }
#pragma unroll
      for (int qc = 0; qc < 8; ++qc) {
        short8 b = *(const short8*)((const char*)W0f +
                    (wb0 + (unsigned)((qc & 1) * 5120 + (qc >> 1) * 40960)));
        acc[0][qc] = MFMA16(ax[0], b, zero4);
        acc[1][qc] = MFMA16(ax[1], b, zero4);
      }
    }
    // kc1..4: h0(t-1) in seg0[1-p]
#pragma unroll 1
    for (int kc = 1; kc < 5; ++kc) {
      short8 am[2];
#pragma unroll
      for (int m = 0; m < 2; ++m)
        am[m] = *(const short8*)(hls + (((rbB + sq) ^ (unsigned)((kc - 1) << 6)) + m * 4096));
#pragma unroll
      for (int qc = 0; qc < 8; ++qc) {
        short8 b = *(const short8*)((const char*)W0f +
                    (wb0 + (unsigned)((qc & 1) * 5120 + (qc >> 1) * 40960 + kc * 1024)));
        acc[0][qc] = MFMA16(am[0], b, acc[0][qc]);
        acc[1][qc] = MFMA16(am[1], b, acc[1][qc]);
      }
    }
    // E0 -> seg0[p]
#pragma unroll
    for (int m = 0; m < 2; ++m)
#pragma unroll
      for (int cc = 0; cc < 2; ++cc) {
        float hv[4];
#pragma unroll
        for (int r = 0; r < 4; ++r) {
          float c = c0s[m][cc][r], h;
          lstm_elem(acc[m][cc][r], acc[m][2 + cc][r], acc[m][4 + cc][r], acc[m][6 + cc][r],
                    nb0[0][cc], nb0[1][cc], nb0[2][cc], nb0[3][cc], c, h);
          c0s[m][cc][r] = c; hv[r] = h;
        }
        unsigned u01 = cvtpk(hv[0], hv[1]);
        unsigned u23 = cvtpk(hv[2], hv[3]);
        const unsigned wa = wbBc[cc] + sp;
        *(unsigned short*)(hls + ((wa ^ 0u)  + m * 4096 + 0))   = (unsigned short)u01;
        *(unsigned short*)(hls + ((wa ^ 16u) + m * 4096 + 256)) = (unsigned short)(u01 >> 16);
        *(unsigned short*)(hls + ((wa ^ 32u) + m * 4096 + 512)) = (unsigned short)u23;
        *(unsigned short*)(hls + ((wa ^ 48u) + m * 4096 + 768)) = (unsigned short)(u23 >> 16);
      }
  };

  auto L1half = [&](int t) {
    const unsigned sp = (unsigned)(t & 1) << 14;
    const unsigned sq = sp ^ 16384u;
    f32x4 acc[2][8];
    // kc0 (peeled): h0(t) in seg0[p]
    {
      short8 am[2];
#pragma unroll
      for (int m = 0; m < 2; ++m)
        am[m] = *(const short8*)(hls + ((rbB + sp) + m * 4096));
#pragma unroll
      for (int qc = 0; qc < 8; ++qc) {
        short8 b = *(const short8*)((const char*)W1f +
                    (wb1 + (unsigned)((qc & 1) * 8192 + (qc >> 1) * 65536)));
        acc[0][qc] = MFMA16(am[0], b, zero4);
        acc[1][qc] = MFMA16(am[1], b, zero4);
      }
    }
#pragma unroll 1
    for (int kc = 1; kc < 4; ++kc) {
      short8 am[2];
#pragma unroll
      for (int m = 0; m < 2; ++m)
        am[m] = *(const short8*)(hls + (((rbB + sp) ^ (unsigned)(kc << 6)) + m * 4096));
#pragma unroll
      for (int qc = 0; qc < 8; ++qc) {
        short8 b = *(const short8*)((const char*)W1f +
                    (wb1 + (unsigned)((qc & 1) * 8192 + (qc >> 1) * 65536 + kc * 1024)));
        acc[0][qc] = MFMA16(am[0], b, acc[0][qc]);
        acc[1][qc] = MFMA16(am[1], b, acc[1][qc]);
      }
    }
    // kc4..7: h1(t-1) in seg1[1-p]
#pragma unroll 1
    for (int kc = 4; kc < 8; ++kc) {
      short8 am[2];
#pragma unroll
      for (int m = 0; m < 2; ++m)
        am[m] = *(const short8*)(hls + (((rbB + 32768u + sq) ^ (unsigned)((kc - 4) << 6)) + m * 4096));
#pragma unroll
      for (int qc = 0; qc < 8; ++qc) {
        short8 b = *(const short8*)((const char*)W1f +
                    (wb1 + (unsigned)((qc & 1) * 8192 + (qc >> 1) * 65536 + kc * 1024)));
        acc[0][qc] = MFMA16(am[0], b, acc[0][qc]);
        acc[1][qc] = MFMA16(am[1], b, acc[1][qc]);
      }
    }
    // E1 -> seg1[p]
#pragma unroll
    for (int m = 0; m < 2; ++m)
#pragma unroll
      for (int cc = 0; cc < 2; ++cc) {
        float hv[4];
#pragma unroll
        for (int r = 0; r < 4; ++r) {
          float c = c1s[m][cc][r], h;
          lstm_elem(acc[m][cc][r], acc[m][2 + cc][r], acc[m][4 + cc][r], acc[m][6 + cc][r],
                    nb1[0][cc], nb1[1][cc], nb1[2][cc], nb1[3][cc], c, h);
          c1s[m][cc][r] = c; hv[r] = h;
        }
        unsigned u01 = cvtpk(hv[0], hv[1]);
        unsigned u23 = cvtpk(hv[2], hv[3]);
        const unsigned wa = wbBc[cc] + 32768u + sp;
        *(unsigned short*)(hls + ((wa ^ 0u)  + m * 4096 + 0))   = (unsigned short)u01;
        *(unsigned short*)(hls + ((wa ^ 16u) + m * 4096 + 256)) = (unsigned short)(u01 >> 16);
        *(unsigned short*)(hls + ((wa ^ 32u) + m * 4096 + 512)) = (unsigned short)u23;
        *(unsigned short*)(hls + ((wa ^ 48u) + m * 4096 + 768)) = (unsigned short)(u23 >> 16);
      }
  };

  // ---- staggered main loop: B one half-step behind A ----------------------
  for (int t = 0; t < 28; ++t) {
    if (g == 0) L0half(t);
    else if (t > 0) L1half(t - 1);
    BAR_LDS();
    if (g == 0) L1half(t);
    else L0half(t);
    BAR_LDS();
  }
  if (g == 1) L1half(27);   // tail: B finishes its last layer-1 half
  __syncthreads();

  // ---------------- final h_n / c_n stores --------------------------------
  // t=27 parity p=1: h0(27) in seg0[1] = +16384, h1(27) in seg1[1] = +49152.
#pragma unroll
  for (int m = 0; m < 2; ++m)
#pragma unroll
    for (int cc = 0; cc < 2; ++cc)
#pragma unroll
      for (int r = 0; r < 4; ++r) {
        int row = g * 32 + m * 16 + lq * 4 + r;
        int col = gw * 32 + cc * 16 + lr;
        size_t o = (size_t)(b0 + row) * 128 + col;
        unsigned roff = (unsigned)(r << 4);
        float h0 = bf2f(*(const unsigned short*)(hls +
                     (((wbBc[cc] + 16384u) ^ roff) + m * 4096 + r * 256)));
        float h1 = bf2f(*(const unsigned short*)(hls +
                     (((wbBc[cc] + 49152u) ^ roff) + m * 4096 + r * 256)));
        out[163840 + o] = h0;                 // h_n layer 0
        out[4358144 + o] = c0s[m][cc][r];     // c_n layer 0
        out[2260992 + o] = h1;                // h_n layer 1
        out[6455296 + o] = c1s[m][cc][r];     // c_n layer 1
      }

  // ---------------- logits = h1(27) @ fc_w^T + fc_b ------------------------
  for (int it = tid; it < 640; it += 512) {
    const unsigned short* h1f = (const unsigned short*)(hls + 49152);
    int bl = it / 10, o = it % 10;
    float s = fc_b[o];
#pragma unroll
    for (int kc8 = 0; kc8 < 16; ++kc8) {
      short8 hv = *(const short8*)(h1f + bl * 128 + ((kc8 ^ (bl & 15)) << 3));
      const float* wp = fc_w + o * 128 + kc8 * 8;
#pragma unroll
      for (int j = 0; j < 8; ++j) s += bf2f((unsigned short)hv[j]) * wp[j];
    }
    out[(size_t)(b0 + bl) * 10 + o] = s;
  }
}

extern "C" void kernel_launch(void* const* d_in, const int* in_sizes, int n_in,
                              void* d_out, int out_size, void* d_ws, size_t ws_size,
                              hipStream_t stream) {
  const float* x       = (const float*)d_in[0];
  const float* w_ih_l0 = (const float*)d_in[1];
  const float* w_hh_l0 = (const float*)d_in[2];
  const float* b_ih_l0 = (const float*)d_in[3];
  const float* b_hh_l0 = (const float*)d_in[4];
  const float* w_ih_l1 = (const float*)d_in[5];
  const float* w_hh_l1 = (const float*)d_in[6];
  const float* b_ih_l1 = (const float*)d_in[7];
  const float* b_hh_l1 = (const float*)d_in[8];
  const float* fc_w    = (const float*)d_in[9];
  const float* fc_b    = (const float*)d_in[10];

  unsigned short* W0f = (unsigned short*)d_ws;            // 32*5*64*8 = 81920 ush
  unsigned short* W1f = W0f + 32 * 5 * 64 * 8;            // 32*8*64*8 = 131072 ush
  float* out = (float*)d_out;

  hipLaunchKernelGGL(prep_weights, dim3(104), dim3(256), 0, stream,
                     w_ih_l0, w_hh_l0, w_ih_l1, w_hh_l1, W0f, W1f);
  hipLaunchKernelGGL(lstm_fused, dim3(256), dim3(512), 0, stream,
                     x, b_ih_l0, b_hh_l0, b_ih_l1, b_hh_l1, fc_w, fc_b, W0f, W1f, out);
}